// Round 8
// baseline (78.278 us; speedup 1.0000x reference)
//
#include <hip/hip_runtime.h>
#include <hip/hip_bf16.h>

#define MM 128      // molecules
#define NA 21       // atoms
#define DD 210      // descriptors
#define DP 224      // padded descriptors
#define TT 4096     // training points
#define NC 64       // t-chunks for phase A
#define CHT 64      // t per chunk (== wave width)
#define MTA 8       // kA m-tile
#define KW 56       // K-range per wave (224/4)
#define GSTR 17     // Gred LDS row stride (odd -> 2-way conflicts max)
#define KCH2 32     // kB K-chunks
#define KLEN2 128   // TT / KCH2
#define WPAD 4      // kB W-tile pad

#define QF   0.22360679774997896f   // sqrt(5)/10
#define Q2F  0.05f                  // Q^2
#define K0E  0.016666666666666666f  // 5/(3*SIG^2)
#define INVQ 4.47213595499958f      // 1/Q

// ---- workspace layout (float offsets) ----
#define OFF_TRP  0                        // [TT][DP]
#define OFF_JXP  (OFF_TRP + TT*DP)        // [TT][DP]
#define OFF_TRPT (OFF_JXP + TT*DP)        // [DP][TT]
#define OFF_JXPT (OFF_TRPT + DP*TT)       // [DP][TT]
#define OFF_XSP  (OFF_JXPT + DP*TT)       // [MM][DP]
#define OFF_NT   (OFF_XSP + MM*DP)        // [TT]
#define OFF_CT   (OFF_NT + TT)            // [TT]
#define OFF_NM   (OFF_CT + TT)            // [MM]
#define OFF_S1P  (OFF_NM + MM)            // [NC][MM]
#define OFF_EP   (OFF_S1P + NC*MM)        // [NC][MM]
#define OFF_W1   (OFF_EP + NC*MM)         // [MM][TT]
#define OFF_W2   (OFF_W1 + MM*TT)         // [MM][TT]
#define OFF_P1   (OFF_W2 + MM*TT)         // [KCH2][MM][DP]
#define OFF_P2   (OFF_P1 + KCH2*MM*DP)    // [KCH2][MM][DP]
// total ~6.6M floats = 26.4 MB

// ---------- K0: blocks [0,128): 32-t tiles -> trp/jxp + trpT/jxpT + nt/ct
// ----------     blocks [128,256): per-molecule descriptors xs + nm ----------
__global__ __launch_bounds__(256) void k0_prep(
        const float* __restrict__ tr, const float* __restrict__ jx,
        const float* __restrict__ Rs,
        float* __restrict__ trp, float* __restrict__ jxp,
        float* __restrict__ trpT, float* __restrict__ jxpT,
        float* __restrict__ nt, float* __restrict__ ct,
        float* __restrict__ xsp, float* __restrict__ nmg) {
    __shared__ float S1[32][225];
    __shared__ float S2[32][225];
    int b = blockIdx.x, tid = threadIdx.x;

    if (b < 128) {
        int t0 = b * 32;
        for (int i = tid; i < 32 * 224; i += 256) {
            int t = i / 224, d = i - t * 224;
            float v1 = 0.f, v2 = 0.f;
            if (d < DD) { v1 = tr[(t0 + t) * DD + d]; v2 = jx[(t0 + t) * DD + d]; }
            S1[t][d] = v1; S2[t][d] = v2;
            trp[(t0 + t) * DP + d] = v1;
            jxp[(t0 + t) * DP + d] = v2;
        }
        __syncthreads();
        if (tid < 64) {
            int t = tid & 31, h = tid >> 5;
            float sn = 0.f, sc = 0.f;
            int d0 = h * 112;
            for (int d = d0; d < d0 + 112; ++d) {
                float v1 = S1[t][d];
                sn = fmaf(v1, v1, sn);
                sc = fmaf(v1, S2[t][d], sc);
            }
            sn += __shfl_xor(sn, 32);
            sc += __shfl_xor(sc, 32);
            if (h == 0) { nt[t0 + t] = sn; ct[t0 + t] = sc; }
        }
        for (int i = tid; i < 224 * 32; i += 256) {
            int d = i >> 5, t = i & 31;
            trpT[d * TT + t0 + t] = S1[t][d];
            jxpT[d * TT + t0 + t] = S2[t][d];
        }
    } else {
        int m = b - 128;
        float* Rl  = &S1[0][0];
        float* red = &S2[0][0];
        if (tid < NA * 3) Rl[tid] = Rs[m * NA * 3 + tid];
        __syncthreads();
        float v = 0.f;
        if (tid < DP) {
            float x = 0.f;
            if (tid < DD) {
                int d = tid;
                int a = (int)((1.0f + sqrtf(8.0f * (float)d + 1.0f)) * 0.5f);
                while (a * (a - 1) / 2 > d) --a;
                while ((a + 1) * a / 2 <= d) ++a;
                int bb = d - a * (a - 1) / 2;
                float dx = Rl[a * 3 + 0] - Rl[bb * 3 + 0];
                float dy = Rl[a * 3 + 1] - Rl[bb * 3 + 1];
                float dz = Rl[a * 3 + 2] - Rl[bb * 3 + 2];
                x = 1.0f / sqrtf(dx * dx + dy * dy + dz * dz);
            }
            xsp[m * DP + tid] = x;
            v = x * x;
        }
        #pragma unroll
        for (int off = 32; off >= 1; off >>= 1) v += __shfl_xor(v, off);
        if ((tid & 63) == 0) red[tid >> 6] = v;
        __syncthreads();
        if (tid == 0) nmg[m] = red[0] + red[1] + red[2] + red[3];
    }
}

// ---------- kA: phase A GEMM (K split across waves) -> W1,W2 + s1/E partials ----------
// grid (NC=64, MM/8=16) = 1024 blocks, 256 thr. Wave my: k in [my*56, my*56+56).
// Thread (my, tx): 8 m x 1 t over 56 k. Cross-wave G reduce via LDS, epilogue
// writes W coalesced to global.
#define KA_LOAD(bt, bj, KK) do { \
    _Pragma("unroll") \
    for (int u = 0; u < 8; ++u) { \
        bt[u] = tb[(KK + u) * TT]; \
        bj[u] = jb[(KK + u) * TT]; \
    } \
} while (0)

#define KA_FMA(bt, bj, KK) do { \
    _Pragma("unroll") \
    for (int u = 0; u < 8; ++u) { \
        float4 a = *(const float4*)&xst[(KK + u) * MTA]; \
        float4 bq = *(const float4*)&xst[(KK + u) * MTA + 4]; \
        g1[0] = fmaf(a.x,  bt[u], g1[0]); \
        g1[1] = fmaf(a.y,  bt[u], g1[1]); \
        g1[2] = fmaf(a.z,  bt[u], g1[2]); \
        g1[3] = fmaf(a.w,  bt[u], g1[3]); \
        g1[4] = fmaf(bq.x, bt[u], g1[4]); \
        g1[5] = fmaf(bq.y, bt[u], g1[5]); \
        g1[6] = fmaf(bq.z, bt[u], g1[6]); \
        g1[7] = fmaf(bq.w, bt[u], g1[7]); \
        g2[0] = fmaf(a.x,  bj[u], g2[0]); \
        g2[1] = fmaf(a.y,  bj[u], g2[1]); \
        g2[2] = fmaf(a.z,  bj[u], g2[2]); \
        g2[3] = fmaf(a.w,  bj[u], g2[3]); \
        g2[4] = fmaf(bq.x, bj[u], g2[4]); \
        g2[5] = fmaf(bq.y, bj[u], g2[5]); \
        g2[6] = fmaf(bq.z, bj[u], g2[6]); \
        g2[7] = fmaf(bq.w, bj[u], g2[7]); \
    } \
} while (0)

__global__ __launch_bounds__(256) void kA_phaseA(
        const float* __restrict__ trpT, const float* __restrict__ jxpT,
        const float* __restrict__ xsp, const float* __restrict__ nt,
        const float* __restrict__ ct, const float* __restrict__ nm,
        float* __restrict__ W1, float* __restrict__ W2,
        float* __restrict__ S1P, float* __restrict__ EP) {
    __shared__ __align__(16) float xst[224 * MTA];       // [k][m], 7.2 KB
    __shared__ float Gr[4 * 64 * GSTR];                  // 17.4 KB
    int tid = threadIdx.x;
    int c = blockIdx.x, m0 = blockIdx.y * MTA;
    int t0 = c * CHT;
    int tx = tid & 63, my = tid >> 6;

    // stage xs tile [k][m] (conflict-free LDS writes: consecutive tid -> consecutive addr)
    for (int i = tid; i < 224 * MTA; i += 256) {
        int k = i >> 3, m = i & 7;
        xst[i] = xsp[(m0 + m) * DP + k];
    }
    __syncthreads();

    // K-split register GEMM: 7 slabs of 8 k, 2-slab pipeline
    float g1[8] = {0.f, 0.f, 0.f, 0.f, 0.f, 0.f, 0.f, 0.f};
    float g2[8] = {0.f, 0.f, 0.f, 0.f, 0.f, 0.f, 0.f, 0.f};
    int kb = my * KW;
    const float* tb = trpT + t0 + tx;
    const float* jb = jxpT + t0 + tx;
    {
        float p0t[8], p0j[8], p1t[8], p1j[8];
        KA_LOAD(p0t, p0j, kb + 0);
        KA_LOAD(p1t, p1j, kb + 8);  KA_FMA(p0t, p0j, kb + 0);
        KA_LOAD(p0t, p0j, kb + 16); KA_FMA(p1t, p1j, kb + 8);
        KA_LOAD(p1t, p1j, kb + 24); KA_FMA(p0t, p0j, kb + 16);
        KA_LOAD(p0t, p0j, kb + 32); KA_FMA(p1t, p1j, kb + 24);
        KA_LOAD(p1t, p1j, kb + 40); KA_FMA(p0t, p0j, kb + 32);
        KA_LOAD(p0t, p0j, kb + 48); KA_FMA(p1t, p1j, kb + 40);
        KA_FMA(p0t, p0j, kb + 48);
    }

    // cross-wave reduce staging
    int base = (my * 64 + tx) * GSTR;
    #pragma unroll
    for (int j = 0; j < 8; ++j) {
        Gr[base + j]     = g1[j];
        Gr[base + 8 + j] = g2[j];
    }
    __syncthreads();

    // epilogue: 512 cells (8m x 64t) over 256 threads -> 2 cells each
    float ntv = nt[t0 + tx], ctv = ct[t0 + tx];
    float s1l[2], el[2];
    #pragma unroll
    for (int cell = 0; cell < 2; ++cell) {
        int m = my + cell * 4;
        float g1s = Gr[(0 * 64 + tx) * GSTR + m] + Gr[(1 * 64 + tx) * GSTR + m]
                  + Gr[(2 * 64 + tx) * GSTR + m] + Gr[(3 * 64 + tx) * GSTR + m];
        float g2s = Gr[(0 * 64 + tx) * GSTR + 8 + m] + Gr[(1 * 64 + tx) * GSTR + 8 + m]
                  + Gr[(2 * 64 + tx) * GSTR + 8 + m] + Gr[(3 * 64 + tx) * GSTR + 8 + m];
        float nmv = nm[m0 + m];
        float d2 = Q2F * (nmv + ntv - 2.f * g1s);
        float xd = sqrtf(fmaxf(d2, 0.f));
        float e  = K0E * __expf(-xd);
        float dv = QF * (g2s - ctv);
        float w1 = e * dv;
        float w2 = e * (1.f + xd);
        W1[(m0 + m) * TT + t0 + tx] = w1;
        W2[(m0 + m) * TT + t0 + tx] = w2;
        s1l[cell] = w1;
        el[cell]  = w2 * dv;
    }
    #pragma unroll
    for (int off = 32; off >= 1; off >>= 1) {
        #pragma unroll
        for (int cell = 0; cell < 2; ++cell) {
            s1l[cell] += __shfl_xor(s1l[cell], off);
            el[cell]  += __shfl_xor(el[cell], off);
        }
    }
    if (tx == 0) {
        S1P[c * MM + m0 + my]     = s1l[0];
        S1P[c * MM + m0 + my + 4] = s1l[1];
        EP [c * MM + m0 + my]     = el[0];
        EP [c * MM + m0 + my + 4] = el[1];
    }
}

// ---------- kB: phase B partial GEMM (KCH2=32), no atomics ----------
// grid (32, 8, 4) = 1024 blocks; 17 KB LDS -> 4 blocks/CU.
__global__ __launch_bounds__(256) void kB_partial(
        const float* __restrict__ W1, const float* __restrict__ W2,
        const float* __restrict__ trp, const float* __restrict__ jxp,
        float* __restrict__ P1, float* __restrict__ P2) {
    __shared__ __align__(16) float Wl1[16][KLEN2 + WPAD];
    __shared__ __align__(16) float Wl2[16][KLEN2 + WPAD];
    int tid = threadIdx.x;
    int c  = blockIdx.x;
    int mt = blockIdx.y;
    int ds = blockIdx.z;
    int t0 = c * KLEN2, m0 = mt * 16;

    // cooperative W tile load: 16 x 128 = 512 float4 per array
    for (int i = tid; i < 512; i += 256) {
        int row = i >> 5;            // 32 f4 per row
        int col = (i & 31) << 2;
        *(float4*)&Wl1[row][col] = *(const float4*)&W1[(m0 + row) * TT + t0 + col];
        *(float4*)&Wl2[row][col] = *(const float4*)&W2[(m0 + row) * TT + t0 + col];
    }
    __syncthreads();
    if (tid >= 224) return;

    int dq = tid % 14, mloc = tid / 14;
    int d0 = ds * 56 + dq * 4;

    float4 a1 = {0.f, 0.f, 0.f, 0.f};
    float4 a2 = {0.f, 0.f, 0.f, 0.f};
    for (int t = 0; t < KLEN2; t += 8) {
        float4 x1[8], x2[8];
        #pragma unroll
        for (int tt = 0; tt < 8; ++tt) {
            int rbase = (t0 + t + tt) * DP + d0;
            x1[tt] = *(const float4*)&trp[rbase];
            x2[tt] = *(const float4*)&jxp[rbase];
        }
        float4 wA1 = *(const float4*)&Wl1[mloc][t];
        float4 wB1 = *(const float4*)&Wl1[mloc][t + 4];
        float4 wA2 = *(const float4*)&Wl2[mloc][t];
        float4 wB2 = *(const float4*)&Wl2[mloc][t + 4];
        float w1a[8] = {wA1.x, wA1.y, wA1.z, wA1.w, wB1.x, wB1.y, wB1.z, wB1.w};
        float w2a[8] = {wA2.x, wA2.y, wA2.z, wA2.w, wB2.x, wB2.y, wB2.z, wB2.w};
        #pragma unroll
        for (int tt = 0; tt < 8; ++tt) {
            a1.x = fmaf(w1a[tt], x1[tt].x, a1.x);
            a1.y = fmaf(w1a[tt], x1[tt].y, a1.y);
            a1.z = fmaf(w1a[tt], x1[tt].z, a1.z);
            a1.w = fmaf(w1a[tt], x1[tt].w, a1.w);
            a2.x = fmaf(w2a[tt], x2[tt].x, a2.x);
            a2.y = fmaf(w2a[tt], x2[tt].y, a2.y);
            a2.z = fmaf(w2a[tt], x2[tt].z, a2.z);
            a2.w = fmaf(w2a[tt], x2[tt].w, a2.w);
        }
    }
    int m = m0 + mloc;
    *(float4*)&P1[((size_t)c * MM + m) * DP + d0] = a1;
    *(float4*)&P2[((size_t)c * MM + m) * DP + d0] = a2;
}

// ---------- K4: chunk-reduce + final forces + energies ----------
__global__ __launch_bounds__(256) void k4_final(
        const float* __restrict__ Rs, const float* __restrict__ xsp,
        const float* __restrict__ P1, const float* __restrict__ P2,
        const float* __restrict__ S1P, const float* __restrict__ EP,
        float* __restrict__ out) {
    int m = blockIdx.x, tid = threadIdx.x;
    __shared__ float fxs[DD];
    __shared__ float Rl[64];
    __shared__ float sE[2];
    if (tid < NA * 3) Rl[tid] = Rs[m * NA * 3 + tid];
    if (tid >= 64 && tid < 128) {      // wave 1: reduce s1/E over NC=64 chunks
        int cc = tid - 64;
        float s = S1P[cc * MM + m];
        float e = EP [cc * MM + m];
        #pragma unroll
        for (int off = 32; off >= 1; off >>= 1) {
            s += __shfl_xor(s, off);
            e += __shfl_xor(e, off);
        }
        if (cc == 0) { sE[0] = s; sE[1] = e; }
    }
    float pa = 0.f, pb = 0.f;
    if (tid < DD) {
        for (int cc = 0; cc < KCH2; ++cc) {
            pa += P1[((size_t)cc * MM + m) * DP + tid];
            pb += P2[((size_t)cc * MM + m) * DP + tid];
        }
    }
    __syncthreads();
    if (tid < DD)
        fxs[tid] = QF * xsp[m * DP + tid] * sE[0] - QF * pa - pb;
    __syncthreads();
    if (tid < NA * 3) {
        int b = tid / 3, c = tid - b * 3;
        float acc = 0.f;
        #pragma unroll
        for (int a = 0; a < NA; ++a) {
            if (a == b) continue;
            int hi = a > b ? a : b, lo = a > b ? b : a;
            int d = hi * (hi - 1) / 2 + lo;
            float dx = Rl[a * 3 + 0] - Rl[b * 3 + 0];
            float dy = Rl[a * 3 + 1] - Rl[b * 3 + 1];
            float dz = Rl[a * 3 + 2] - Rl[b * 3 + 2];
            float r2 = dx * dx + dy * dy + dz * dz;
            float ir = 1.0f / sqrtf(r2);
            float w = fxs[d] * ir * ir * ir;
            float comp = (c == 0) ? dx : ((c == 1) ? dy : dz);
            acc = fmaf(w, comp, acc);
        }
        out[MM + m * NA * 3 + tid] = acc;
    }
    if (tid == 0) out[m] = sE[1] * INVQ;
}

extern "C" void kernel_launch(void* const* d_in, const int* in_sizes, int n_in,
                              void* d_out, int out_size, void* d_ws, size_t ws_size,
                              hipStream_t stream) {
    const float* Rs = (const float*)d_in[0];
    const float* tr = (const float*)d_in[1];
    const float* jx = (const float*)d_in[2];
    float* out = (float*)d_out;
    float* ws = (float*)d_ws;

    float* trp  = ws + OFF_TRP;
    float* jxp  = ws + OFF_JXP;
    float* trpT = ws + OFF_TRPT;
    float* jxpT = ws + OFF_JXPT;
    float* xsp  = ws + OFF_XSP;
    float* nt   = ws + OFF_NT;
    float* ct   = ws + OFF_CT;
    float* nm   = ws + OFF_NM;
    float* S1P  = ws + OFF_S1P;
    float* EP   = ws + OFF_EP;
    float* W1   = ws + OFF_W1;
    float* W2   = ws + OFF_W2;
    float* P1   = ws + OFF_P1;
    float* P2   = ws + OFF_P2;

    k0_prep<<<256, 256, 0, stream>>>(tr, jx, Rs, trp, jxp, trpT, jxpT, nt, ct, xsp, nm);
    kA_phaseA<<<dim3(NC, MM / MTA), 256, 0, stream>>>(trpT, jxpT, xsp, nt, ct, nm, W1, W2, S1P, EP);
    kB_partial<<<dim3(KCH2, MM / 16, 4), 256, 0, stream>>>(W1, W2, trp, jxp, P1, P2);
    k4_final<<<MM, 256, 0, stream>>>(Rs, xsp, P1, P2, S1P, EP, out);
}